// Round 14
// baseline (512.474 us; speedup 1.0000x reference)
//
#include <hip/hip_runtime.h>
#include <stdint.h>

#define BATCH 32
#define HWD 224
#define HP 14
#define NP (BATCH * HP * HP)   // 6272 patches = 49 * 128
#define DIM 768
#define K0 512
#define K1 2048
#define K2 8192

typedef unsigned long long ull;
typedef unsigned int uint;
typedef __attribute__((ext_vector_type(8))) short bf16x8;
typedef __attribute__((ext_vector_type(4))) float f32x4;

__device__ __forceinline__ uint fkey(float f) {
    uint u = __float_as_uint(f);
    return (u & 0x80000000u) ? ~u : (u | 0x80000000u);  // monotone fp32 -> u32
}
__device__ __forceinline__ short f2bf(float f) {       // round-to-nearest-even bf16
    uint u = __float_as_uint(f);
    uint r = (u + 0x7fffu + ((u >> 16) & 1u)) >> 16;
    return (short)r;
}
__device__ __forceinline__ float bf2f(short h) {
    return __uint_as_float(((uint)(unsigned short)h) << 16);
}
__device__ __forceinline__ ull umin64(ull a, ull b) { return a < b ? a : b; }
__device__ __forceinline__ ull umax64(ull a, ull b) { return a > b ? a : b; }

// ---------------- patchify + bf16 hi/lo split (residual kept as hi/lo pair) ----------------
__global__ void patchify_split_kernel(const float* __restrict__ data,
                                      short* __restrict__ xh, short* __restrict__ xl) {
    int gid = blockIdx.x * 256 + threadIdx.x;   // covers NP*DIM exactly
    int d = gid % DIM;
    int p = gid / DIM;
    int b = p / 196; int t = p % 196; int i = t / 14, j = t % 14;
    int ch = d >> 8; int r = d & 255; int py = r >> 4; int px = r & 15;
    float v = data[((b * 3 + ch) * HWD + i * 16 + py) * HWD + j * 16 + px];
    short h = f2bf(v);
    xh[gid] = h;
    xl[gid] = f2bf(v - bf2f(h));
}

// ---------------- center prep: bf16 hi + exact fp32 row norms ----------------
__global__ void cprep_kernel(const float* __restrict__ c, short* __restrict__ ch,
                             float* __restrict__ nrm) {
    int lane = threadIdx.x & 63;
    int row = blockIdx.x * 4 + (threadIdx.x >> 6);
    const float* src = c + (size_t)row * DIM;
    float s = 0.f;
    #pragma unroll
    for (int i = 0; i < 12; ++i) {
        int d = lane + i * 64;
        float v = src[d];
        ch[(size_t)row * DIM + d] = f2bf(v);
        s += v * v;
    }
    #pragma unroll
    for (int off = 32; off; off >>= 1) s += __shfl_xor(s, off, 64);
    if (lane == 0) nrm[row] = s;
}

// ---------------- MFMA classify (verified 16x16x32 layouts) ----------------
// Occupancy ledger (R12/R13 measured): unified demand = 64 acc + ~72 arch =
// 136 > 128 -> cap(256,4) spilled ~10 regs (WRITE 44 MB, 192 us) while
// uncapped sat at 3 blocks (183 us). R14: shave arch by 12 regs via compute
// LOOP SWAP -- outer u holds one fch (4 regs), inner i re-reads fxh from LDS
// per MFMA (4 regs live) instead of a 16-reg fxh[4] array. Arch ~60 ->
// unified ~124 <= 128 -> 4 blocks/CU WITHOUT spill. LDS reads/step 8 -> 20
// (~2.6k cyc/CU at 4 blocks, under the 4.4k wall; LDS was ~27% utilized).
// Spill detector: WRITE_SIZE >> 13 MB => fallback to (256,3).
// Kept: R8 by-fast XCD swizzle (FETCH -7x), R6 single-term score, 2-buf
// 32 KB LDS, 2-phase __syncthreads schedule, SGPR-hoisted descriptors,
// MH=4 all levels (R12's MH=2 regression reverted).
template<int MH>
__global__ __launch_bounds__(256, 4) void classify16(
    const short* __restrict__ xh,
    const short* __restrict__ chv,
    const float* __restrict__ nrm,
    ull* __restrict__ partB, ull* __restrict__ partS2)
{
    constexpr int CH0 = MH * 128;           // ch slot base (2*MH A-tiles * 64)
    constexpr int SLOTS = CH0 + 512;        // per-buffer slots (16 B each)
    constexpr int NJ = (2 * MH + 8) / 4;    // staging instrs per wave (4)
    constexpr int GX = NP / (MH * 32);      // x-blocks (49)
    __shared__ __align__(16) short lds[2 * SLOTS * 8];   // 32 KB (2-buffer)

    // by-fast XCD swizzle: xcd owns a contiguous by-band; by varies fastest
    // within the XCD so each bx's xh chunk is reused across ypx by-values.
    int bx = blockIdx.x, by = blockIdx.y;
    if ((gridDim.y & 7) == 0) {
        int P = blockIdx.x + GX * blockIdx.y;
        int xcd = P & 7;
        int wofs = P >> 3;
        int ypx = gridDim.y >> 3;
        by = xcd * ypx + (wofs % ypx);
        bx = wofs / ypx;
    }

    const int tid = threadIdx.x;
    const int lane = tid & 63;
    const int w = tid >> 6;
    const int wm = w & 1, wn = w >> 1;
    const int pbase = bx * (MH * 32);
    const int n0 = by * 128;

    // staging descriptors, SGPR-hoisted: base ptr per group in SGPR pair,
    // one shared per-lane offset VGPR; group g covers slots [region+t*64,+64).
    const short* gbase[NJ];
    int lsl[NJ];
    const int laneoff = (lane & 15) * DIM + ((lane >> 4) * 8);
    #pragma unroll
    for (int j = 0; j < NJ; ++j) {
        int g = j * 4 + w;                  // 2*MH A groups, then 8 ch groups
        const short* base; int rb, sb, t;
        if (g < 2 * MH) { base = xh;  rb = pbase; sb = 0;    t = g; }
        else            { base = chv; rb = n0;    sb = CH0;  t = g - 2 * MH; }
        ull b64 = (ull)(base + (size_t)(rb + t * 16) * DIM);   // wave-uniform
        uint lo = __builtin_amdgcn_readfirstlane((uint)b64);
        uint hi = __builtin_amdgcn_readfirstlane((uint)(b64 >> 32));
        gbase[j] = (const short*)(((ull)hi << 32) | lo);
        lsl[j] = __builtin_amdgcn_readfirstlane(sb + t * 64);
    }

    f32x4 acc[MH][4];
    #pragma unroll
    for (int i = 0; i < MH; ++i)
        #pragma unroll
        for (int u = 0; u < 4; ++u) acc[i][u] = (f32x4){0.f, 0.f, 0.f, 0.f};

    auto stage = [&](int buf, int kt) {     // kt = K-tile index, dc = kt*32
        const int off = buf * SLOTS;
        #pragma unroll
        for (int j = 0; j < NJ; ++j) {
            __builtin_amdgcn_global_load_lds(
                (const __attribute__((address_space(1))) void*)(gbase[j] + laneoff + kt * 32),
                (__attribute__((address_space(3))) void*)(lds + (size_t)(off + lsl[j]) * 8),
                16, 0, 0);
        }
    };
    // loop-swapped compute: 1 fch + 1 fxh live (8 regs) instead of fxh[4]
    // (16 regs held across the u-loop). fxh re-read from LDS per MFMA.
    auto compute = [&](int buf) {
        const bf16x8* Lc = (const bf16x8*)lds + buf * SLOTS;
        #pragma unroll
        for (int u = 0; u < 4; ++u) {
            bf16x8 fch = Lc[CH0 + (wn * 4 + u) * 64 + lane];
            #pragma unroll
            for (int i = 0; i < MH; ++i) {
                bf16x8 fxh = Lc[(wm * MH + i) * 64 + lane];
                acc[i][u] = __builtin_amdgcn_mfma_f32_16x16x32_bf16(fxh, fch, acc[i][u], 0, 0, 0);
            }
        }
    };

    // ---- 2-buffer 2-phase K-loop: 24 K-tiles of 32 (R1 schedule) ----
    stage(0, 0);
    __syncthreads();
    #pragma unroll 4
    for (int t = 0; t < 24; ++t) {
        if (t + 1 < 24) stage((t + 1) & 1, t + 1);   // prefetch next tile
        compute(t & 1);
        if (t < 23) __syncthreads();                 // drains vmcnt(0)
    }

    // epilogue: per-row top-2 over this block's wave-half (64 centers)
    float nor[4]; uint ncol[4];
    #pragma unroll
    for (int u = 0; u < 4; ++u) {
        ncol[u] = (uint)(n0 + (wn * 4 + u) * 16 + (lane & 15));
        nor[u] = nrm[ncol[u]];
    }
    const int pw = 2 * gridDim.y;           // partials per row
    #pragma unroll
    for (int i = 0; i < MH; ++i) {
        #pragma unroll
        for (int reg = 0; reg < 4; ++reg) {
            ull b = ~0ull, s2 = ~0ull;
            #pragma unroll
            for (int u = 0; u < 4; ++u) {
                float s = fmaf(-2.f, acc[i][u][reg], nor[u]);
                ull pk = ((ull)fkey(s) << 32) | ncol[u];
                ull nb = umin64(b, pk);
                s2 = umin64(s2, umax64(b, pk));
                b = nb;
            }
            #pragma unroll
            for (int off = 1; off <= 8; off <<= 1) {   // reduce across lane&15
                ull ob = __shfl_xor(b, off, 64);
                ull os2 = __shfl_xor(s2, off, 64);
                ull nb = umin64(b, ob);
                s2 = umin64(umin64(s2, os2), umax64(b, ob));
                b = nb;
            }
            if ((lane & 15) == 0) {
                int row = pbase + (wm * MH + i) * 16 + (lane >> 4) * 4 + reg;
                size_t o = (size_t)row * pw + (size_t)by * 2 + wn;
                partB[o] = b;
                partS2[o] = s2;
            }
        }
    }
}

// ---------------- merge partials + exact fp32 top-4 rescue + residual update ----------------
// nsplit = partials per row (stride); strided merge loop handles any count.
// R14: xh/xl loads/stores vectorized (uint = 2 bf16, d = c*128 + lane*2),
// center reads as float2 (G13 — scalar bf16 ~2x slower, measured m146).
__global__ void merge_rescue_update(
    short* __restrict__ xh, short* __restrict__ xl,
    const float* __restrict__ cent, const float* __restrict__ nrm,
    const ull* __restrict__ partB, const ull* __restrict__ partS2,
    int nsplit, int* __restrict__ cls)
{
    int lane = threadIdx.x & 63;
    int p = blockIdx.x * 4 + (threadIdx.x >> 6);
    ull a = ~0ull, c = ~0ull;
    for (int j = lane; j < nsplit; j += 64) {
        ull b2 = partB[(size_t)p * nsplit + j];
        ull s2b = partS2[(size_t)p * nsplit + j];
        ull na = umin64(a, b2);
        c = umin64(umin64(c, s2b), umax64(a, b2));
        a = na;
    }
    // extract top-4 candidates (packed keys unique: idx appears once)
    int idx[4];
    #pragma unroll
    for (int r = 0; r < 4; ++r) {
        ull m = a;
        #pragma unroll
        for (int off = 32; off; off >>= 1) m = umin64(m, __shfl_xor(m, off, 64));
        idx[r] = (int)(m & 0xFFFFFFFFull);
        if (a == m) { a = c; c = ~0ull; }   // pop from owning lane
    }
    // x reconstructed once into registers (vectorized: 2 bf16 per uint)
    float xv[12];
    #pragma unroll
    for (int cc = 0; cc < 6; ++cc) {
        int d = cc * 128 + lane * 2;
        uint vh = *(const uint*)(xh + (size_t)p * DIM + d);
        uint vl = *(const uint*)(xl + (size_t)p * DIM + d);
        xv[2 * cc]     = bf2f((short)(vh & 0xFFFFu)) + bf2f((short)(vl & 0xFFFFu));
        xv[2 * cc + 1] = bf2f((short)(vh >> 16))     + bf2f((short)(vl >> 16));
    }
    float dot[4] = {0.f, 0.f, 0.f, 0.f};
    #pragma unroll
    for (int r = 0; r < 4; ++r) {
        const float* cr = cent + (size_t)idx[r] * DIM;
        #pragma unroll
        for (int cc = 0; cc < 6; ++cc) {
            float2 cv = *(const float2*)(cr + cc * 128 + lane * 2);
            dot[r] = fmaf(xv[2 * cc], cv.x, fmaf(xv[2 * cc + 1], cv.y, dot[r]));
        }
    }
    #pragma unroll
    for (int r = 0; r < 4; ++r)
        #pragma unroll
        for (int off = 32; off; off >>= 1) dot[r] += __shfl_xor(dot[r], off, 64);
    ull best = ~0ull;
    #pragma unroll
    for (int r = 0; r < 4; ++r) {
        float sc = fmaf(-2.f, dot[r], nrm[idx[r]]);
        best = umin64(best, ((ull)fkey(sc) << 32) | (uint)idx[r]);  // ties -> lower idx
    }
    int cw = (int)(best & 0xFFFFFFFFull);
    if (lane == 0) cls[p] = cw;
    const float* cwr = cent + (size_t)cw * DIM;
    #pragma unroll
    for (int cc = 0; cc < 6; ++cc) {
        int d = cc * 128 + lane * 2;
        float2 cv = *(const float2*)(cwr + d);
        float nx0 = xv[2 * cc]     - cv.x;
        float nx1 = xv[2 * cc + 1] - cv.y;
        short h0 = f2bf(nx0), h1 = f2bf(nx1);
        short l0 = f2bf(nx0 - bf2f(h0)), l1 = f2bf(nx1 - bf2f(h1));
        *(uint*)(xh + (size_t)p * DIM + d) = (uint)(unsigned short)h0 | ((uint)(unsigned short)h1 << 16);
        *(uint*)(xl + (size_t)p * DIM + d) = (uint)(unsigned short)l0 | ((uint)(unsigned short)l1 << 16);
    }
}

// ---------------- embed + diff outputs (LDS transpose, coalesced writes) ----------------
__global__ void embdiff_kernel(const short* __restrict__ xh, const short* __restrict__ xl,
    const int* __restrict__ cls0, const int* __restrict__ cls1, const int* __restrict__ cls2,
    const float* __restrict__ e0, const float* __restrict__ e1, const float* __restrict__ e2,
    float* __restrict__ out)
{
    __shared__ float s[196][65];
    int b = blockIdx.x / 12;
    int dc = (blockIdx.x % 12) * 64;
    int tid = threadIdx.x;
    int dl = tid & 63;
    // embed
    for (int it = 0; it < 49; ++it) {
        int pl = it * 4 + (tid >> 6);
        int p = b * 196 + pl;
        int d = dc + dl;
        s[pl][dl] = e0[(size_t)cls0[p] * DIM + d] + e1[(size_t)cls1[p] * DIM + d]
                  + e2[(size_t)cls2[p] * DIM + d];
    }
    __syncthreads();
    if (tid < 196) {
        for (int d = 0; d < 64; ++d)
            out[((size_t)b * DIM + dc + d) * 196 + tid] = s[tid][d];
    }
    __syncthreads();
    // diff (residual = xh + xl)
    for (int it = 0; it < 49; ++it) {
        int pl = it * 4 + (tid >> 6);
        size_t o = (size_t)(b * 196 + pl) * DIM + dc + dl;
        s[pl][dl] = bf2f(xh[o]) + bf2f(xl[o]);
    }
    __syncthreads();
    if (tid < 196) {
        float* od = out + 2 * (size_t)NP * DIM;
        for (int d = 0; d < 64; ++d)
            od[((size_t)b * DIM + dc + d) * 196 + tid] = s[tid][d];
    }
}

// ---------------- img_sum output ----------------
__global__ void img_kernel(
    const int* __restrict__ cls0, const int* __restrict__ cls1, const int* __restrict__ cls2,
    const float* __restrict__ c0, const float* __restrict__ c1, const float* __restrict__ c2,
    float* __restrict__ out)
{
    __shared__ float s[14][256];
    int bi = blockIdx.x;
    int b = bi / 42; int rem = bi % 42; int ch = rem / 14; int i = rem % 14;
    int tid = threadIdx.x;
    for (int j = 0; j < 14; ++j) {
        int p = b * 196 + i * 14 + j;
        int d = ch * 256 + tid;
        s[j][tid] = c0[(size_t)cls0[p] * DIM + d] + c1[(size_t)cls1[p] * DIM + d]
                  + c2[(size_t)cls2[p] * DIM + d];
    }
    __syncthreads();
    float* oi = out + (size_t)NP * DIM;
    if (tid < 224) {
        int j = tid >> 4, px = tid & 15;
        for (int py = 0; py < 16; ++py)
            oi[(((size_t)b * 3 + ch) * HWD + i * 16 + py) * HWD + tid] = s[j][py * 16 + px];
    }
}

extern "C" void kernel_launch(void* const* d_in, const int* in_sizes, int n_in,
                              void* d_out, int out_size, void* d_ws, size_t ws_size,
                              hipStream_t stream) {
    const float* data = (const float*)d_in[0];
    const float* c0 = (const float*)d_in[1];
    const float* c1 = (const float*)d_in[2];
    const float* c2 = (const float*)d_in[3];
    const float* e0 = (const float*)d_in[4];
    const float* e1 = (const float*)d_in[5];
    const float* e2 = (const float*)d_in[6];
    float* out = (float*)d_out;

    char* w = (char*)d_ws;
    short* xh = (short*)w;    w += (size_t)NP * DIM * 2;      // 9.63 MB
    short* xl = (short*)w;    w += (size_t)NP * DIM * 2;      // 9.63 MB
    short* chB = (short*)w;   w += (size_t)K2 * DIM * 2;      // 12.58 MB
    float* nrm = (float*)w;   w += (size_t)K2 * 4;            // 32 KB
    ull* partB = (ull*)w;     w += (size_t)NP * 128 * 8;      // 6.42 MB
    ull* partS2 = (ull*)w;    w += (size_t)NP * 128 * 8;      // 6.42 MB
    int* cls0 = (int*)w;      w += (size_t)NP * 4;
    int* cls1 = (int*)w;      w += (size_t)NP * 4;
    int* cls2 = (int*)w;      w += (size_t)NP * 4;
    // total ~44.9 MiB

    patchify_split_kernel<<<(NP * DIM) / 256, 256, 0, stream>>>(data, xh, xl);

    // level 0: K=512, M=128 -> grid (49,4), 8 partials (no swizzle: 4%8!=0)
    cprep_kernel<<<K0 / 4, 256, 0, stream>>>(c0, chB, nrm);
    classify16<4><<<dim3(NP / 128, K0 / 128), 256, 0, stream>>>(xh, chB, nrm, partB, partS2);
    merge_rescue_update<<<NP / 4, 256, 0, stream>>>(xh, xl, c0, nrm, partB, partS2, 8, cls0);

    // level 1: K=2048, M=128 -> grid (49,16), 32 partials (swizzled, by-fast)
    cprep_kernel<<<K1 / 4, 256, 0, stream>>>(c1, chB, nrm);
    classify16<4><<<dim3(NP / 128, K1 / 128), 256, 0, stream>>>(xh, chB, nrm, partB, partS2);
    merge_rescue_update<<<NP / 4, 256, 0, stream>>>(xh, xl, c1, nrm, partB, partS2, 32, cls1);

    // level 2: K=8192, M=128 -> grid (49,64), 128 partials (swizzled, by-fast)
    cprep_kernel<<<K2 / 4, 256, 0, stream>>>(c2, chB, nrm);
    classify16<4><<<dim3(NP / 128, K2 / 128), 256, 0, stream>>>(xh, chB, nrm, partB, partS2);
    merge_rescue_update<<<NP / 4, 256, 0, stream>>>(xh, xl, c2, nrm, partB, partS2, 128, cls2);

    embdiff_kernel<<<BATCH * 12, 256, 0, stream>>>(xh, xl, cls0, cls1, cls2, e0, e1, e2, out);
    img_kernel<<<BATCH * 3 * 14, 256, 0, stream>>>(cls0, cls1, cls2, c0, c1, c2, out);
}

// Round 15
// 454.344 us; speedup vs baseline: 1.1279x; 1.1279x over previous
//
#include <hip/hip_runtime.h>
#include <stdint.h>

#define BATCH 32
#define HWD 224
#define HP 14
#define NP (BATCH * HP * HP)   // 6272 patches = 49 * 128
#define DIM 768
#define K0 512
#define K1 2048
#define K2 8192
#define KTOT (K0 + K1 + K2)    // 10752 center rows total

typedef unsigned long long ull;
typedef unsigned int uint;
typedef __attribute__((ext_vector_type(8))) short bf16x8;
typedef __attribute__((ext_vector_type(4))) float f32x4;

__device__ __forceinline__ uint fkey(float f) {
    uint u = __float_as_uint(f);
    return (u & 0x80000000u) ? ~u : (u | 0x80000000u);  // monotone fp32 -> u32
}
__device__ __forceinline__ short f2bf(float f) {       // round-to-nearest-even bf16
    uint u = __float_as_uint(f);
    uint r = (u + 0x7fffu + ((u >> 16) & 1u)) >> 16;
    return (short)r;
}
__device__ __forceinline__ float bf2f(short h) {
    return __uint_as_float(((uint)(unsigned short)h) << 16);
}
__device__ __forceinline__ ull umin64(ull a, ull b) { return a < b ? a : b; }
__device__ __forceinline__ ull umax64(ull a, ull b) { return a > b ? a : b; }

// ---------------- patchify + bf16 hi/lo split (residual kept as hi/lo pair) ----------------
__global__ void patchify_split_kernel(const float* __restrict__ data,
                                      short* __restrict__ xh, short* __restrict__ xl) {
    int gid = blockIdx.x * 256 + threadIdx.x;   // covers NP*DIM exactly
    int d = gid % DIM;
    int p = gid / DIM;
    int b = p / 196; int t = p % 196; int i = t / 14, j = t % 14;
    int ch = d >> 8; int r = d & 255; int py = r >> 4; int px = r & 15;
    float v = data[((b * 3 + ch) * HWD + i * 16 + py) * HWD + j * 16 + px];
    short h = f2bf(v);
    xh[gid] = h;
    xl[gid] = f2bf(v - bf2f(h));
}

// ---------------- center prep (FUSED, all 3 levels): bf16 hi + fp32 row norms ----------------
// R15: one launch for K0+K1+K2 = 10752 rows; per-level regions at row offsets
// 0 / K0 / K0+K1 in ch[] and nrm[]. Independent of classify results, so all
// prep cost is paid up-front in a single dispatch (was 3).
__global__ void cprep_all_kernel(const float* __restrict__ c0, const float* __restrict__ c1,
                                 const float* __restrict__ c2,
                                 short* __restrict__ ch, float* __restrict__ nrm) {
    int lane = threadIdx.x & 63;
    int row = blockIdx.x * 4 + (threadIdx.x >> 6);   // 0..10751
    const float* src;
    if (row < K0)           src = c0 + (size_t)row * DIM;
    else if (row < K0 + K1) src = c1 + (size_t)(row - K0) * DIM;
    else                    src = c2 + (size_t)(row - K0 - K1) * DIM;
    float s = 0.f;
    #pragma unroll
    for (int i = 0; i < 12; ++i) {
        int d = lane + i * 64;
        float v = src[d];
        ch[(size_t)row * DIM + d] = f2bf(v);
        s += v * v;
    }
    #pragma unroll
    for (int off = 32; off; off >>= 1) s += __shfl_xor(s, off, 64);
    if (lane == 0) nrm[row] = s;
}

// ---------------- MFMA classify (verified 16x16x32 layouts) — R8 configuration ----------------
// BEST-KNOWN config (R8, measured 458.7 us total / 182 us L2, no spill):
// single-term xh.ch score (R6; exact fp32 top-4 rescue absorbs bf16 noise),
// 3-buffer 48 KB LDS pipeline w/ counted vmcnt (R5), by-fast XCD swizzle
// (R8: FETCH -7x), (256,3) so unified 136 regs fit w/o spill at 3 blocks/CU.
// 4-blocks/CU lever falsified 3x (R11/R13/R14: cap 128 -> ~8-reg spill,
// WRITE_SIZE 44-62 MB, net regression). M/N tile variants falsified
// (R9 NB=256 reg-A; R12 M=64 L0/L1). Schedule variants neutral (R1/R5).
__global__ __launch_bounds__(256, 3) void classify16(
    const short* __restrict__ xh,
    const short* __restrict__ chv,
    const float* __restrict__ nrm,
    ull* __restrict__ partB, ull* __restrict__ partS2)
{
    constexpr int NHT = 4;
    constexpr int NB = 128;                 // block N
    constexpr int CH0 = 512;                // ch slot base
    constexpr int SLOTS = 1024;             // 16 KB per buffer
    constexpr int NJ = 4;                   // staging instrs per wave
    constexpr int GX = NP / 128;            // 49 x-blocks
    __shared__ __align__(16) short lds[3 * SLOTS * 8];   // 48 KB (3-buffer)

    // by-fast XCD swizzle: xcd owns a contiguous by-band; by varies FASTEST
    // within the XCD so each bx's xh chunk is reused across ypx by-values
    // (steady-state staging = L2 hits; FETCH 310->44 MB measured).
    int bx = blockIdx.x, by = blockIdx.y;
    if ((gridDim.y & 7) == 0) {
        int P = blockIdx.x + GX * blockIdx.y;
        int xcd = P & 7;
        int wofs = P >> 3;
        int ypx = gridDim.y >> 3;
        by = xcd * ypx + (wofs % ypx);
        bx = wofs / ypx;
    }

    const int tid = threadIdx.x;
    const int lane = tid & 63;
    const int w = tid >> 6;
    const int wm = w & 1, wn = w >> 1;
    const int pbase = bx * 128;
    const int n0 = by * NB;

    // staging descriptors: group g covers slots [region + t*64, +64)
    const short* gp[NJ];
    int ls[NJ];
    #pragma unroll
    for (int j = 0; j < NJ; ++j) {
        int g = j * 4 + w;                  // 0..15: 8 xh groups, 8 ch groups
        const short* base; int rb, sb, t;
        if (g < 8) { base = xh;  rb = pbase; sb = 0;    t = g; }
        else       { base = chv; rb = n0;    sb = CH0;  t = g - 8; }
        gp[j] = base + (size_t)(rb + t * 16 + (lane & 15)) * DIM + ((lane >> 4) * 8);
        ls[j] = sb + t * 64;
    }

    f32x4 acc[4][NHT];
    #pragma unroll
    for (int i = 0; i < 4; ++i)
        #pragma unroll
        for (int u = 0; u < NHT; ++u) acc[i][u] = (f32x4){0.f, 0.f, 0.f, 0.f};

    auto stage = [&](int buf, int kt) {     // kt = K-tile index, dc = kt*32
        const int off = buf * SLOTS;
        #pragma unroll
        for (int j = 0; j < NJ; ++j) {
            __builtin_amdgcn_global_load_lds(
                (const __attribute__((address_space(1))) void*)(gp[j] + kt * 32),
                (__attribute__((address_space(3))) void*)(lds + (size_t)(off + ls[j]) * 8),
                16, 0, 0);
        }
    };
    auto compute = [&](int buf) {
        const bf16x8* Lc = (const bf16x8*)lds + buf * SLOTS;
        bf16x8 fxh[4];
        #pragma unroll
        for (int i = 0; i < 4; ++i)
            fxh[i] = Lc[(wm * 4 + i) * 64 + lane];
        #pragma unroll
        for (int u = 0; u < NHT; ++u) {
            bf16x8 fch = Lc[CH0 + (wn * NHT + u) * 64 + lane];
            #pragma unroll
            for (int i = 0; i < 4; ++i)
                acc[i][u] = __builtin_amdgcn_mfma_f32_16x16x32_bf16(fxh[i], fch, acc[i][u], 0, 0, 0);
        }
    };

    // ---- 3-buffer pipelined K-loop: 24 K-tiles of 32 ----
    stage(0, 0);
    stage(1, 1);
    asm volatile("s_waitcnt vmcnt(4)" ::: "memory");   // tile 0 landed
    __builtin_amdgcn_s_barrier();
    __builtin_amdgcn_sched_barrier(0);

    #pragma unroll 3
    for (int t = 0; t < 24; ++t) {
        if (t + 2 < 24) stage((t + 2) % 3, t + 2);   // issue tile t+2
        compute(t % 3);                              // consume tile t
        if (t < 23) {
            // guarantee tile t+1's LDS writes landed; leave tile t+2 in flight
            if (t + 2 < 24) asm volatile("s_waitcnt vmcnt(4)" ::: "memory");
            else            asm volatile("s_waitcnt vmcnt(0)" ::: "memory");
            __builtin_amdgcn_s_barrier();
            __builtin_amdgcn_sched_barrier(0);
        }
    }

    // epilogue: per-row top-2 over this block's wave-half (64 centers)
    float nor[NHT]; uint ncol[NHT];
    #pragma unroll
    for (int u = 0; u < NHT; ++u) {
        ncol[u] = (uint)(n0 + (wn * NHT + u) * 16 + (lane & 15));
        nor[u] = nrm[ncol[u]];
    }
    const int pw = 2 * gridDim.y;           // partials per row
    #pragma unroll
    for (int i = 0; i < 4; ++i) {
        #pragma unroll
        for (int reg = 0; reg < 4; ++reg) {
            ull b = ~0ull, s2 = ~0ull;
            #pragma unroll
            for (int u = 0; u < NHT; ++u) {
                float s = fmaf(-2.f, acc[i][u][reg], nor[u]);
                ull pk = ((ull)fkey(s) << 32) | ncol[u];
                ull nb = umin64(b, pk);
                s2 = umin64(s2, umax64(b, pk));
                b = nb;
            }
            #pragma unroll
            for (int off = 1; off <= 8; off <<= 1) {   // reduce across lane&15
                ull ob = __shfl_xor(b, off, 64);
                ull os2 = __shfl_xor(s2, off, 64);
                ull nb = umin64(b, ob);
                s2 = umin64(umin64(s2, os2), umax64(b, ob));
                b = nb;
            }
            if ((lane & 15) == 0) {
                int row = pbase + (wm * 4 + i) * 16 + (lane >> 4) * 4 + reg;
                size_t o = (size_t)row * pw + (size_t)by * 2 + wn;
                partB[o] = b;
                partS2[o] = s2;
            }
        }
    }
}

// ---------------- merge partials + exact fp32 top-4 rescue + residual update ----------------
// nsplit = partials per row (stride); strided merge loop handles any count.
__global__ void merge_rescue_update(
    short* __restrict__ xh, short* __restrict__ xl,
    const float* __restrict__ cent, const float* __restrict__ nrm,
    const ull* __restrict__ partB, const ull* __restrict__ partS2,
    int nsplit, int* __restrict__ cls)
{
    int lane = threadIdx.x & 63;
    int p = blockIdx.x * 4 + (threadIdx.x >> 6);
    ull a = ~0ull, c = ~0ull;
    for (int j = lane; j < nsplit; j += 64) {
        ull b2 = partB[(size_t)p * nsplit + j];
        ull s2b = partS2[(size_t)p * nsplit + j];
        ull na = umin64(a, b2);
        c = umin64(umin64(c, s2b), umax64(a, b2));
        a = na;
    }
    // extract top-4 candidates (packed keys unique: idx appears once)
    int idx[4];
    #pragma unroll
    for (int r = 0; r < 4; ++r) {
        ull m = a;
        #pragma unroll
        for (int off = 32; off; off >>= 1) m = umin64(m, __shfl_xor(m, off, 64));
        idx[r] = (int)(m & 0xFFFFFFFFull);
        if (a == m) { a = c; c = ~0ull; }   // pop from owning lane
    }
    // x reconstructed once into registers
    float xv[12];
    #pragma unroll
    for (int i = 0; i < 12; ++i) {
        int d = lane + i * 64;
        xv[i] = bf2f(xh[(size_t)p * DIM + d]) + bf2f(xl[(size_t)p * DIM + d]);
    }
    float dot[4] = {0.f, 0.f, 0.f, 0.f};
    #pragma unroll
    for (int r = 0; r < 4; ++r) {
        const float* cr = cent + (size_t)idx[r] * DIM;
        #pragma unroll
        for (int i = 0; i < 12; ++i) dot[r] = fmaf(xv[i], cr[lane + i * 64], dot[r]);
    }
    #pragma unroll
    for (int r = 0; r < 4; ++r)
        #pragma unroll
        for (int off = 32; off; off >>= 1) dot[r] += __shfl_xor(dot[r], off, 64);
    ull best = ~0ull;
    #pragma unroll
    for (int r = 0; r < 4; ++r) {
        float sc = fmaf(-2.f, dot[r], nrm[idx[r]]);
        best = umin64(best, ((ull)fkey(sc) << 32) | (uint)idx[r]);  // ties -> lower idx
    }
    int cw = (int)(best & 0xFFFFFFFFull);
    if (lane == 0) cls[p] = cw;
    const float* cwr = cent + (size_t)cw * DIM;
    #pragma unroll
    for (int i = 0; i < 12; ++i) {
        int d = lane + i * 64;
        float nx = xv[i] - cwr[d];
        short h = f2bf(nx);
        xh[(size_t)p * DIM + d] = h;
        xl[(size_t)p * DIM + d] = f2bf(nx - bf2f(h));
    }
}

// ---------------- embed + diff outputs (LDS transpose, coalesced writes) ----------------
__global__ void embdiff_kernel(const short* __restrict__ xh, const short* __restrict__ xl,
    const int* __restrict__ cls0, const int* __restrict__ cls1, const int* __restrict__ cls2,
    const float* __restrict__ e0, const float* __restrict__ e1, const float* __restrict__ e2,
    float* __restrict__ out)
{
    __shared__ float s[196][65];
    int b = blockIdx.x / 12;
    int dc = (blockIdx.x % 12) * 64;
    int tid = threadIdx.x;
    int dl = tid & 63;
    // embed
    for (int it = 0; it < 49; ++it) {
        int pl = it * 4 + (tid >> 6);
        int p = b * 196 + pl;
        int d = dc + dl;
        s[pl][dl] = e0[(size_t)cls0[p] * DIM + d] + e1[(size_t)cls1[p] * DIM + d]
                  + e2[(size_t)cls2[p] * DIM + d];
    }
    __syncthreads();
    if (tid < 196) {
        for (int d = 0; d < 64; ++d)
            out[((size_t)b * DIM + dc + d) * 196 + tid] = s[tid][d];
    }
    __syncthreads();
    // diff (residual = xh + xl)
    for (int it = 0; it < 49; ++it) {
        int pl = it * 4 + (tid >> 6);
        size_t o = (size_t)(b * 196 + pl) * DIM + dc + dl;
        s[pl][dl] = bf2f(xh[o]) + bf2f(xl[o]);
    }
    __syncthreads();
    if (tid < 196) {
        float* od = out + 2 * (size_t)NP * DIM;
        for (int d = 0; d < 64; ++d)
            od[((size_t)b * DIM + dc + d) * 196 + tid] = s[tid][d];
    }
}

// ---------------- img_sum output ----------------
__global__ void img_kernel(
    const int* __restrict__ cls0, const int* __restrict__ cls1, const int* __restrict__ cls2,
    const float* __restrict__ c0, const float* __restrict__ c1, const float* __restrict__ c2,
    float* __restrict__ out)
{
    __shared__ float s[14][256];
    int bi = blockIdx.x;
    int b = bi / 42; int rem = bi % 42; int ch = rem / 14; int i = rem % 14;
    int tid = threadIdx.x;
    for (int j = 0; j < 14; ++j) {
        int p = b * 196 + i * 14 + j;
        int d = ch * 256 + tid;
        s[j][tid] = c0[(size_t)cls0[p] * DIM + d] + c1[(size_t)cls1[p] * DIM + d]
                  + c2[(size_t)cls2[p] * DIM + d];
    }
    __syncthreads();
    float* oi = out + (size_t)NP * DIM;
    if (tid < 224) {
        int j = tid >> 4, px = tid & 15;
        for (int py = 0; py < 16; ++py)
            oi[(((size_t)b * 3 + ch) * HWD + i * 16 + py) * HWD + tid] = s[j][py * 16 + px];
    }
}

extern "C" void kernel_launch(void* const* d_in, const int* in_sizes, int n_in,
                              void* d_out, int out_size, void* d_ws, size_t ws_size,
                              hipStream_t stream) {
    const float* data = (const float*)d_in[0];
    const float* c0 = (const float*)d_in[1];
    const float* c1 = (const float*)d_in[2];
    const float* c2 = (const float*)d_in[3];
    const float* e0 = (const float*)d_in[4];
    const float* e1 = (const float*)d_in[5];
    const float* e2 = (const float*)d_in[6];
    float* out = (float*)d_out;

    char* w = (char*)d_ws;
    short* xh = (short*)w;    w += (size_t)NP * DIM * 2;      // 9.63 MB
    short* xl = (short*)w;    w += (size_t)NP * DIM * 2;      // 9.63 MB
    short* chB = (short*)w;   w += (size_t)KTOT * DIM * 2;    // 16.5 MB (all 3 levels)
    float* nrm = (float*)w;   w += (size_t)KTOT * 4;          // 43 KB
    ull* partB = (ull*)w;     w += (size_t)NP * 128 * 8;      // 6.42 MB
    ull* partS2 = (ull*)w;    w += (size_t)NP * 128 * 8;      // 6.42 MB
    int* cls0 = (int*)w;      w += (size_t)NP * 4;
    int* cls1 = (int*)w;      w += (size_t)NP * 4;
    int* cls2 = (int*)w;      w += (size_t)NP * 4;
    // total ~48.8 MiB

    patchify_split_kernel<<<(NP * DIM) / 256, 256, 0, stream>>>(data, xh, xl);
    cprep_all_kernel<<<KTOT / 4, 256, 0, stream>>>(c0, c1, c2, chB, nrm);

    // level 0: K=512 -> grid (49,4), 8 partials (no swizzle: 4%8!=0)
    classify16<<<dim3(NP / 128, K0 / 128), 256, 0, stream>>>(
        xh, chB, nrm, partB, partS2);
    merge_rescue_update<<<NP / 4, 256, 0, stream>>>(xh, xl, c0, nrm, partB, partS2, 8, cls0);

    // level 1: K=2048 -> grid (49,16), 32 partials (swizzled, by-fast)
    classify16<<<dim3(NP / 128, K1 / 128), 256, 0, stream>>>(
        xh, chB + (size_t)K0 * DIM, nrm + K0, partB, partS2);
    merge_rescue_update<<<NP / 4, 256, 0, stream>>>(xh, xl, c1, nrm + K0, partB, partS2, 32, cls1);

    // level 2: K=8192 -> grid (49,64), 128 partials (swizzled, by-fast)
    classify16<<<dim3(NP / 128, K2 / 128), 256, 0, stream>>>(
        xh, chB + (size_t)(K0 + K1) * DIM, nrm + K0 + K1, partB, partS2);
    merge_rescue_update<<<NP / 4, 256, 0, stream>>>(xh, xl, c2, nrm + K0 + K1, partB, partS2, 128, cls2);

    embdiff_kernel<<<BATCH * 12, 256, 0, stream>>>(xh, xl, cls0, cls1, cls2, e0, e1, e2, out);
    img_kernel<<<BATCH * 3 * 14, 256, 0, stream>>>(cls0, cls1, cls2, c0, c1, c2, out);
}

// Round 16
// 432.084 us; speedup vs baseline: 1.1861x; 1.0515x over previous
//
#include <hip/hip_runtime.h>
#include <stdint.h>

#define BATCH 32
#define HWD 224
#define HP 14
#define NP (BATCH * HP * HP)   // 6272 patches = 49 * 128
#define DIM 768
#define K0 512
#define K1 2048
#define K2 8192
#define KTOT (K0 + K1 + K2)    // 10752 center rows total

typedef unsigned long long ull;
typedef unsigned int uint;
typedef __attribute__((ext_vector_type(8))) short bf16x8;
typedef __attribute__((ext_vector_type(4))) float f32x4;

__device__ __forceinline__ uint fkey(float f) {
    uint u = __float_as_uint(f);
    return (u & 0x80000000u) ? ~u : (u | 0x80000000u);  // monotone fp32 -> u32
}
__device__ __forceinline__ short f2bf(float f) {       // round-to-nearest-even bf16
    uint u = __float_as_uint(f);
    uint r = (u + 0x7fffu + ((u >> 16) & 1u)) >> 16;
    return (short)r;
}
__device__ __forceinline__ float bf2f(short h) {
    return __uint_as_float(((uint)(unsigned short)h) << 16);
}
__device__ __forceinline__ ull umin64(ull a, ull b) { return a < b ? a : b; }
__device__ __forceinline__ ull umax64(ull a, ull b) { return a > b ? a : b; }

// ---------------- patchify + bf16 hi/lo split (residual kept as hi/lo pair) ----------------
__global__ void patchify_split_kernel(const float* __restrict__ data,
                                      short* __restrict__ xh, short* __restrict__ xl) {
    int gid = blockIdx.x * 256 + threadIdx.x;   // covers NP*DIM exactly
    int d = gid % DIM;
    int p = gid / DIM;
    int b = p / 196; int t = p % 196; int i = t / 14, j = t % 14;
    int ch = d >> 8; int r = d & 255; int py = r >> 4; int px = r & 15;
    float v = data[((b * 3 + ch) * HWD + i * 16 + py) * HWD + j * 16 + px];
    short h = f2bf(v);
    xh[gid] = h;
    xl[gid] = f2bf(v - bf2f(h));
}

// ---------------- center prep (FUSED, all 3 levels): bf16 hi + fp32 row norms ----------------
__global__ void cprep_all_kernel(const float* __restrict__ c0, const float* __restrict__ c1,
                                 const float* __restrict__ c2,
                                 short* __restrict__ ch, float* __restrict__ nrm) {
    int lane = threadIdx.x & 63;
    int row = blockIdx.x * 4 + (threadIdx.x >> 6);   // 0..10751
    const float* src;
    if (row < K0)           src = c0 + (size_t)row * DIM;
    else if (row < K0 + K1) src = c1 + (size_t)(row - K0) * DIM;
    else                    src = c2 + (size_t)(row - K0 - K1) * DIM;
    float s = 0.f;
    #pragma unroll
    for (int i = 0; i < 12; ++i) {
        int d = lane + i * 64;
        float v = src[d];
        ch[(size_t)row * DIM + d] = f2bf(v);
        s += v * v;
    }
    #pragma unroll
    for (int off = 32; off; off >>= 1) s += __shfl_xor(s, off, 64);
    if (lane == 0) nrm[row] = s;
}

// ---------------- MFMA classify (verified 16x16x32 layouts) ----------------
// R16: FATTER STEPS. Measured law (R5 vs R7): CU-level step cost ~1.5k cyc is
// WORK-INSENSITIVE (32 vs 16 MFMA/wave/step -> same 4.4k wall at 3 blocks/CU).
// So double N per block (NB=256, NHT=8): 2x MFMA per step at ~the same wall,
// halving total block-steps (L2: 75k -> 37.6k). Both operands stay in LDS
// (R9's reg-A version was broken by uncoalesced loads); buffer = 24 KB
// (= R5's SLOTS=1536), 3-buffer 72 KB -> 2 blocks/CU (144 KB LDS).
// acc = 128 AGPR + ~70 arch ~ 200 unified -> (256,2) cap 256: NO spill
// (R10/R11/R13/R14 spill modes impossible), 2 waves/SIMD.
// Kept verbatim: R5 3-buffer counted-vmcnt(NJ=6) schedule, R8 by-fast XCD
// swizzle (identity when gridY%8!=0), R6 single-term score + exact fp32
// top-4 rescue (absmax gate 0.03125), R15 fused cprep.
__global__ __launch_bounds__(256, 2) void classify16(
    const short* __restrict__ xh,
    const short* __restrict__ chv,
    const float* __restrict__ nrm,
    ull* __restrict__ partB, ull* __restrict__ partS2)
{
    constexpr int NHT = 8;                  // 8 n-tiles per wave (N=256/block)
    constexpr int NB = 256;                 // block N
    constexpr int CH0 = 512;                // ch slot base (8 A-tiles * 64)
    constexpr int SLOTS = 512 + 128 * NHT;  // 1536 slots = 24 KB per buffer
    constexpr int NJ = 6;                   // staging instrs per wave (24 groups / 4 waves)
    constexpr int GX = NP / 128;            // 49 x-blocks
    __shared__ __align__(16) short lds[3 * SLOTS * 8];   // 72 KB (3-buffer)

    // by-fast XCD swizzle: xcd owns a contiguous by-band; by varies FASTEST
    // within the XCD so each bx's xh chunk is reused across ypx by-values
    // (steady-state staging = L2 hits; FETCH 310->44 MB measured at NB=128).
    int bx = blockIdx.x, by = blockIdx.y;
    if ((gridDim.y & 7) == 0) {
        int P = blockIdx.x + GX * blockIdx.y;
        int xcd = P & 7;
        int wofs = P >> 3;
        int ypx = gridDim.y >> 3;
        by = xcd * ypx + (wofs % ypx);
        bx = wofs / ypx;
    }

    const int tid = threadIdx.x;
    const int lane = tid & 63;
    const int w = tid >> 6;
    const int wm = w & 1, wn = w >> 1;      // wn in {0,1}: 128-col half
    const int pbase = bx * 128;
    const int n0 = by * NB;

    // staging descriptors: group g covers slots [region + t*64, +64)
    // g 0..7: xh tiles; g 8..23: ch tiles (16 tiles of 16 centers).
    const short* gp[NJ];
    int ls[NJ];
    #pragma unroll
    for (int j = 0; j < NJ; ++j) {
        int g = j * 4 + w;
        const short* base; int rb, sb, t;
        if (g < 8) { base = xh;  rb = pbase; sb = 0;    t = g; }
        else       { base = chv; rb = n0;    sb = CH0;  t = g - 8; }
        gp[j] = base + (size_t)(rb + t * 16 + (lane & 15)) * DIM + ((lane >> 4) * 8);
        ls[j] = sb + t * 64;
    }

    f32x4 acc[4][NHT];                      // 128 AGPR
    #pragma unroll
    for (int i = 0; i < 4; ++i)
        #pragma unroll
        for (int u = 0; u < NHT; ++u) acc[i][u] = (f32x4){0.f, 0.f, 0.f, 0.f};

    auto stage = [&](int buf, int kt) {     // kt = K-tile index, dc = kt*32
        const int off = buf * SLOTS;
        #pragma unroll
        for (int j = 0; j < NJ; ++j) {
            __builtin_amdgcn_global_load_lds(
                (const __attribute__((address_space(1))) void*)(gp[j] + kt * 32),
                (__attribute__((address_space(3))) void*)(lds + (size_t)(off + ls[j]) * 8),
                16, 0, 0);
        }
    };
    auto compute = [&](int buf) {
        const bf16x8* Lc = (const bf16x8*)lds + buf * SLOTS;
        bf16x8 fxh[4];
        #pragma unroll
        for (int i = 0; i < 4; ++i)
            fxh[i] = Lc[(wm * 4 + i) * 64 + lane];
        #pragma unroll
        for (int u = 0; u < NHT; ++u) {
            bf16x8 fch = Lc[CH0 + (wn * NHT + u) * 64 + lane];
            #pragma unroll
            for (int i = 0; i < 4; ++i)
                acc[i][u] = __builtin_amdgcn_mfma_f32_16x16x32_bf16(fxh[i], fch, acc[i][u], 0, 0, 0);
        }
    };

    // ---- 3-buffer pipelined K-loop: 24 K-tiles of 32 (R5 schedule, NJ=6) ----
    stage(0, 0);
    stage(1, 1);
    asm volatile("s_waitcnt vmcnt(6)" ::: "memory");   // tile 0 landed
    __builtin_amdgcn_s_barrier();
    __builtin_amdgcn_sched_barrier(0);

    #pragma unroll 3
    for (int t = 0; t < 24; ++t) {
        if (t + 2 < 24) stage((t + 2) % 3, t + 2);   // issue tile t+2
        compute(t % 3);                              // consume tile t
        if (t < 23) {
            // guarantee tile t+1's LDS writes landed; leave tile t+2 in flight
            if (t + 2 < 24) asm volatile("s_waitcnt vmcnt(6)" ::: "memory");
            else            asm volatile("s_waitcnt vmcnt(0)" ::: "memory");
            __builtin_amdgcn_s_barrier();
            __builtin_amdgcn_sched_barrier(0);
        }
    }

    // epilogue: per-row top-2 over this block's wave-half (128 centers)
    float nor[NHT]; uint ncol[NHT];
    #pragma unroll
    for (int u = 0; u < NHT; ++u) {
        ncol[u] = (uint)(n0 + (wn * NHT + u) * 16 + (lane & 15));
        nor[u] = nrm[ncol[u]];
    }
    const int pw = 2 * gridDim.y;           // partials per row
    #pragma unroll
    for (int i = 0; i < 4; ++i) {
        #pragma unroll
        for (int reg = 0; reg < 4; ++reg) {
            ull b = ~0ull, s2 = ~0ull;
            #pragma unroll
            for (int u = 0; u < NHT; ++u) {
                float s = fmaf(-2.f, acc[i][u][reg], nor[u]);
                ull pk = ((ull)fkey(s) << 32) | ncol[u];
                ull nb = umin64(b, pk);
                s2 = umin64(s2, umax64(b, pk));
                b = nb;
            }
            #pragma unroll
            for (int off = 1; off <= 8; off <<= 1) {   // reduce across lane&15
                ull ob = __shfl_xor(b, off, 64);
                ull os2 = __shfl_xor(s2, off, 64);
                ull nb = umin64(b, ob);
                s2 = umin64(umin64(s2, os2), umax64(b, ob));
                b = nb;
            }
            if ((lane & 15) == 0) {
                int row = pbase + (wm * 4 + i) * 16 + (lane >> 4) * 4 + reg;
                size_t o = (size_t)row * pw + (size_t)by * 2 + wn;
                partB[o] = b;
                partS2[o] = s2;
            }
        }
    }
}

// ---------------- merge partials + exact fp32 top-4 rescue + residual update ----------------
// nsplit = partials per row (stride); strided merge loop handles any count.
__global__ void merge_rescue_update(
    short* __restrict__ xh, short* __restrict__ xl,
    const float* __restrict__ cent, const float* __restrict__ nrm,
    const ull* __restrict__ partB, const ull* __restrict__ partS2,
    int nsplit, int* __restrict__ cls)
{
    int lane = threadIdx.x & 63;
    int p = blockIdx.x * 4 + (threadIdx.x >> 6);
    ull a = ~0ull, c = ~0ull;
    for (int j = lane; j < nsplit; j += 64) {
        ull b2 = partB[(size_t)p * nsplit + j];
        ull s2b = partS2[(size_t)p * nsplit + j];
        ull na = umin64(a, b2);
        c = umin64(umin64(c, s2b), umax64(a, b2));
        a = na;
    }
    // extract top-4 candidates (packed keys unique: idx appears once)
    int idx[4];
    #pragma unroll
    for (int r = 0; r < 4; ++r) {
        ull m = a;
        #pragma unroll
        for (int off = 32; off; off >>= 1) m = umin64(m, __shfl_xor(m, off, 64));
        idx[r] = (int)(m & 0xFFFFFFFFull);
        if (a == m) { a = c; c = ~0ull; }   // pop from owning lane
    }
    // x reconstructed once into registers
    float xv[12];
    #pragma unroll
    for (int i = 0; i < 12; ++i) {
        int d = lane + i * 64;
        xv[i] = bf2f(xh[(size_t)p * DIM + d]) + bf2f(xl[(size_t)p * DIM + d]);
    }
    float dot[4] = {0.f, 0.f, 0.f, 0.f};
    #pragma unroll
    for (int r = 0; r < 4; ++r) {
        const float* cr = cent + (size_t)idx[r] * DIM;
        #pragma unroll
        for (int i = 0; i < 12; ++i) dot[r] = fmaf(xv[i], cr[lane + i * 64], dot[r]);
    }
    #pragma unroll
    for (int r = 0; r < 4; ++r)
        #pragma unroll
        for (int off = 32; off; off >>= 1) dot[r] += __shfl_xor(dot[r], off, 64);
    ull best = ~0ull;
    #pragma unroll
    for (int r = 0; r < 4; ++r) {
        float sc = fmaf(-2.f, dot[r], nrm[idx[r]]);
        best = umin64(best, ((ull)fkey(sc) << 32) | (uint)idx[r]);  // ties -> lower idx
    }
    int cw = (int)(best & 0xFFFFFFFFull);
    if (lane == 0) cls[p] = cw;
    const float* cwr = cent + (size_t)cw * DIM;
    #pragma unroll
    for (int i = 0; i < 12; ++i) {
        int d = lane + i * 64;
        float nx = xv[i] - cwr[d];
        short h = f2bf(nx);
        xh[(size_t)p * DIM + d] = h;
        xl[(size_t)p * DIM + d] = f2bf(nx - bf2f(h));
    }
}

// ---------------- embed + diff outputs (LDS transpose, coalesced writes) ----------------
__global__ void embdiff_kernel(const short* __restrict__ xh, const short* __restrict__ xl,
    const int* __restrict__ cls0, const int* __restrict__ cls1, const int* __restrict__ cls2,
    const float* __restrict__ e0, const float* __restrict__ e1, const float* __restrict__ e2,
    float* __restrict__ out)
{
    __shared__ float s[196][65];
    int b = blockIdx.x / 12;
    int dc = (blockIdx.x % 12) * 64;
    int tid = threadIdx.x;
    int dl = tid & 63;
    // embed
    for (int it = 0; it < 49; ++it) {
        int pl = it * 4 + (tid >> 6);
        int p = b * 196 + pl;
        int d = dc + dl;
        s[pl][dl] = e0[(size_t)cls0[p] * DIM + d] + e1[(size_t)cls1[p] * DIM + d]
                  + e2[(size_t)cls2[p] * DIM + d];
    }
    __syncthreads();
    if (tid < 196) {
        for (int d = 0; d < 64; ++d)
            out[((size_t)b * DIM + dc + d) * 196 + tid] = s[tid][d];
    }
    __syncthreads();
    // diff (residual = xh + xl)
    for (int it = 0; it < 49; ++it) {
        int pl = it * 4 + (tid >> 6);
        size_t o = (size_t)(b * 196 + pl) * DIM + dc + dl;
        s[pl][dl] = bf2f(xh[o]) + bf2f(xl[o]);
    }
    __syncthreads();
    if (tid < 196) {
        float* od = out + 2 * (size_t)NP * DIM;
        for (int d = 0; d < 64; ++d)
            od[((size_t)b * DIM + dc + d) * 196 + tid] = s[tid][d];
    }
}

// ---------------- img_sum output ----------------
__global__ void img_kernel(
    const int* __restrict__ cls0, const int* __restrict__ cls1, const int* __restrict__ cls2,
    const float* __restrict__ c0, const float* __restrict__ c1, const float* __restrict__ c2,
    float* __restrict__ out)
{
    __shared__ float s[14][256];
    int bi = blockIdx.x;
    int b = bi / 42; int rem = bi % 42; int ch = rem / 14; int i = rem % 14;
    int tid = threadIdx.x;
    for (int j = 0; j < 14; ++j) {
        int p = b * 196 + i * 14 + j;
        int d = ch * 256 + tid;
        s[j][tid] = c0[(size_t)cls0[p] * DIM + d] + c1[(size_t)cls1[p] * DIM + d]
                  + c2[(size_t)cls2[p] * DIM + d];
    }
    __syncthreads();
    float* oi = out + (size_t)NP * DIM;
    if (tid < 224) {
        int j = tid >> 4, px = tid & 15;
        for (int py = 0; py < 16; ++py)
            oi[(((size_t)b * 3 + ch) * HWD + i * 16 + py) * HWD + tid] = s[j][py * 16 + px];
    }
}

extern "C" void kernel_launch(void* const* d_in, const int* in_sizes, int n_in,
                              void* d_out, int out_size, void* d_ws, size_t ws_size,
                              hipStream_t stream) {
    const float* data = (const float*)d_in[0];
    const float* c0 = (const float*)d_in[1];
    const float* c1 = (const float*)d_in[2];
    const float* c2 = (const float*)d_in[3];
    const float* e0 = (const float*)d_in[4];
    const float* e1 = (const float*)d_in[5];
    const float* e2 = (const float*)d_in[6];
    float* out = (float*)d_out;

    char* w = (char*)d_ws;
    short* xh = (short*)w;    w += (size_t)NP * DIM * 2;      // 9.63 MB
    short* xl = (short*)w;    w += (size_t)NP * DIM * 2;      // 9.63 MB
    short* chB = (short*)w;   w += (size_t)KTOT * DIM * 2;    // 16.5 MB (all 3 levels)
    float* nrm = (float*)w;   w += (size_t)KTOT * 4;          // 43 KB
    ull* partB = (ull*)w;     w += (size_t)NP * 128 * 8;      // 6.42 MB
    ull* partS2 = (ull*)w;    w += (size_t)NP * 128 * 8;      // 6.42 MB
    int* cls0 = (int*)w;      w += (size_t)NP * 4;
    int* cls1 = (int*)w;      w += (size_t)NP * 4;
    int* cls2 = (int*)w;      w += (size_t)NP * 4;
    // total ~48.8 MiB

    patchify_split_kernel<<<(NP * DIM) / 256, 256, 0, stream>>>(data, xh, xl);
    cprep_all_kernel<<<KTOT / 4, 256, 0, stream>>>(c0, c1, c2, chB, nrm);

    // level 0: K=512, NB=256 -> grid (49,2), 4 partials (no swizzle: 2%8!=0)
    classify16<<<dim3(NP / 128, K0 / 256), 256, 0, stream>>>(
        xh, chB, nrm, partB, partS2);
    merge_rescue_update<<<NP / 4, 256, 0, stream>>>(xh, xl, c0, nrm, partB, partS2, 4, cls0);

    // level 1: K=2048, NB=256 -> grid (49,8), 16 partials (swizzled, by-fast)
    classify16<<<dim3(NP / 128, K1 / 256), 256, 0, stream>>>(
        xh, chB + (size_t)K0 * DIM, nrm + K0, partB, partS2);
    merge_rescue_update<<<NP / 4, 256, 0, stream>>>(xh, xl, c1, nrm + K0, partB, partS2, 16, cls1);

    // level 2: K=8192, NB=256 -> grid (49,32), 64 partials (swizzled, by-fast)
    classify16<<<dim3(NP / 128, K2 / 256), 256, 0, stream>>>(
        xh, chB + (size_t)(K0 + K1) * DIM, nrm + K0 + K1, partB, partS2);
    merge_rescue_update<<<NP / 4, 256, 0, stream>>>(xh, xl, c2, nrm + K0 + K1, partB, partS2, 64, cls2);

    embdiff_kernel<<<BATCH * 12, 256, 0, stream>>>(xh, xl, cls0, cls1, cls2, e0, e1, e2, out);
    img_kernel<<<BATCH * 3 * 14, 256, 0, stream>>>(cls0, cls1, cls2, c0, c1, c2, out);
}